// Round 3
// baseline (427.184 us; speedup 1.0000x reference)
//
#include <hip/hip_runtime.h>

#define NTOK 49
#define CDIM 128
#define NH 4
#define NWIN 64

typedef unsigned short u16;
typedef unsigned int u32;
typedef __bf16 bf16x8 __attribute__((ext_vector_type(8)));
typedef float f32x4 __attribute__((ext_vector_type(4)));
typedef u16 u16x4 __attribute__((ext_vector_type(4)));

union Frag { u32 u[4]; bf16x8 v; };

// RNE f32->bf16 via compiler cast (v_cvt-based, 1 VALU op).
__device__ __forceinline__ u16 f2bf(float f) {
  union { __bf16 h; u16 u; } c;
  c.h = (__bf16)f;
  return c.u;
}
__device__ __forceinline__ u32 pack2(float a, float b) {
  return (u32)f2bf(a) | ((u32)f2bf(b) << 16);
}
__device__ __forceinline__ bf16x8 ld8(const u16* p) { return *(const bf16x8*)p; }

// Convert a "transposed C-layout" register tile pair into an MFMA fragment.
// Source: lane ln holds pairs (x0/y0 = tile sel 0, x1/y1 = tile sel 1) packed
// over the index that must become the k-slice. Same pattern for Q, K, P, V.
__device__ __forceinline__ void build_frag(u32 u[4], u32 x0, u32 y0, u32 x1, u32 y1,
                                           int quad, int ln) {
#pragma unroll
  for (int p = 0; p < 4; ++p) {
    int src = ((2 * (quad & 1) + (p >> 1)) << 4) | ln;
    int a0 = __shfl((int)((p & 1) ? y0 : x0), src);
    int a1 = __shfl((int)((p & 1) ? y1 : x1), src);
    u[p] = (u32)((quad < 2) ? a0 : a1);
  }
}

// ---------------- prep: transpose weights to bf16, build combined bias+mask ----
// ws layout (bytes): [0,98304) wqkvT bf16 (384x128)  [98304,131072) wprojT bf16 (128x128)
//                    [131072,131072+4MB) cmb f32 [win][h][q 64][m 64], -1e30 pads
__global__ void prep_kernel(const float* __restrict__ qkv_w,
                            const float* __restrict__ proj_w,
                            const float* __restrict__ bias_table,
                            const float* __restrict__ mask,
                            const int* __restrict__ rel_index,
                            u16* __restrict__ wqkvT,
                            u16* __restrict__ wprojT,
                            float* __restrict__ cmb) {
  int i = blockIdx.x * 256 + threadIdx.x;   // 1,048,576 threads
  if (i < 384 * 128) {
    int n = i >> 7, k = i & 127;
    wqkvT[i] = f2bf(qkv_w[k * 384 + n]);
  }
  if (i < 128 * 128) {
    int n = i >> 7, k = i & 127;
    wprojT[i] = f2bf(proj_w[k * 128 + n]);
  }
  int m = i & 63, q = (i >> 6) & 63, hh = (i >> 12) & 3, win = i >> 14;
  float v = -1e30f;
  if (q < NTOK && m < NTOK)
    v = bias_table[rel_index[q * NTOK + m] * NH + hh] + mask[(win * NTOK + q) * NTOK + m];
  cmb[i] = v;   // cmb[win][h][q][m], coalesced in m
}

// ---------------- fused window attention ----------------
// 256 threads = 4 waves, wave = head. Q/K/V/P all live in REGISTERS; the
// transposes needed between MFMA stages are done with build_frag shuffles
// (swapped-operand MFMA for Q/K gives the transposed C-layout; S is computed
// as S^T so softmax rows are lane-local; P^T packs feed PV directly).
//
// LDS map (u16 units, 17408 total = 34 KB -> 4 blocks/CU = 50% occupancy):
//   XB [0,8192): x bf16 64x128, xor-swizzled 16B chunks (read-only after A)
//   AO [8192 + h*2304): per-head attention output 64x36 (dims 0..31), for
//   the cross-head proj in phase E.
#define AOFF 8192

__device__ __forceinline__ int xsw(int row, int col) {
  return (row << 7) + ((((col >> 3) ^ (row & 15)) << 3) | (col & 7));
}

__global__ __launch_bounds__(256, 4)
void swin_fused(const float* __restrict__ x, const float* __restrict__ qkv_b,
                const float* __restrict__ proj_b, const u16* __restrict__ wqkvT,
                const u16* __restrict__ wprojT, const float* __restrict__ cmb,
                float* __restrict__ out) {
  __shared__ u16 lds[17408];
  const int tid  = threadIdx.x;
  const int head = tid >> 6;
  const int lane = tid & 63;
  const int ln   = lane & 15;
  const int quad = lane >> 4;
  const int b    = blockIdx.x;
  const int win  = b & (NWIN - 1);
  const float scale = 0.17677669529663687f;  // 32^-0.5

  // ---- Phase A: x -> LDS bf16 (rows 49..63 zeroed), coalesced float4 loads ----
  {
    const float4* x4 = (const float4*)(x + (size_t)b * (NTOK * CDIM));
    for (int i = tid; i < (NTOK * CDIM) / 4; i += 256) {
      float4 f = x4[i];
      int e = i << 2;
      int row = e >> 7, col = e & 127;
      u16x4 v;
      v[0] = f2bf(f.x); v[1] = f2bf(f.y); v[2] = f2bf(f.z); v[3] = f2bf(f.w);
      *(u16x4*)&lds[xsw(row, col)] = v;
    }
    for (int i = tid; i < (15 * CDIM) / 4; i += 256) {
      int e = i << 2;
      int row = NTOK + (e >> 7), col = e & 127;
      u16x4 v = {0, 0, 0, 0};
      *(u16x4*)&lds[xsw(row, col)] = v;
    }
  }
  __syncthreads();   // #1: XB ready

  // ---- Phase B: all of Q, K, V -> registers.
  // Q,K via SWAPPED mfma(bw, af): lane holds [ch-local=quad*4+r][tok=ln]
  // (transposed C-layout, packed over channel pairs).
  // V via normal mfma(af, bw): lane holds [tok=quad*4+r][d=ln] (packed over
  // token pairs).
  u32 qx[4][2], qy[4][2], kx[4][2], ky[4][2], vbx[4][2], vby[4][2];
  {
#pragma unroll
    for (int tm = 0; tm < 4; ++tm) {
      bf16x8 af[4];
#pragma unroll
      for (int ks = 0; ks < 4; ++ks)
        af[ks] = ld8(&lds[xsw(tm * 16 + ln, ks * 32 + quad * 8)]);
      // Q (sect 0) and K (sect 1), swapped operands
#pragma unroll
      for (int sect = 0; sect < 2; ++sect) {
#pragma unroll
        for (int tc = 0; tc < 2; ++tc) {
          int colb = sect * 128 + head * 32 + tc * 16;
          bf16x8 bw[4];
#pragma unroll
          for (int ks = 0; ks < 4; ++ks)
            bw[ks] = ld8(wqkvT + (colb + ln) * 128 + ks * 32 + quad * 8);
          f32x4 cb4 = *(const f32x4*)&qkv_b[colb + quad * 4];
          f32x4 acc = {0.f, 0.f, 0.f, 0.f};
#pragma unroll
          for (int ks = 0; ks < 4; ++ks)
            acc = __builtin_amdgcn_mfma_f32_16x16x32_bf16(bw[ks], af[ks], acc, 0, 0, 0);
          if (sect == 0) {
            qx[tm][tc] = pack2((acc[0] + cb4[0]) * scale, (acc[1] + cb4[1]) * scale);
            qy[tm][tc] = pack2((acc[2] + cb4[2]) * scale, (acc[3] + cb4[3]) * scale);
          } else {
            kx[tm][tc] = pack2(acc[0] + cb4[0], acc[1] + cb4[1]);
            ky[tm][tc] = pack2(acc[2] + cb4[2], acc[3] + cb4[3]);
          }
        }
      }
      // V, normal orientation
#pragma unroll
      for (int tc = 0; tc < 2; ++tc) {
        int colg = 256 + head * 32 + tc * 16 + ln;
        bf16x8 bw[4];
#pragma unroll
        for (int ks = 0; ks < 4; ++ks)
          bw[ks] = ld8(wqkvT + colg * 128 + ks * 32 + quad * 8);
        float cb = qkv_b[colg];
        f32x4 acc = {0.f, 0.f, 0.f, 0.f};
#pragma unroll
        for (int ks = 0; ks < 4; ++ks)
          acc = __builtin_amdgcn_mfma_f32_16x16x32_bf16(af[ks], bw[ks], acc, 0, 0, 0);
        vbx[tm][tc] = pack2(acc[0] + cb, acc[1] + cb);
        vby[tm][tc] = pack2(acc[2] + cb, acc[3] + cb);
      }
    }
  }
  // no barrier: phases C/D are pure register/shuffle work, wave-private

  // ---- Phase C+D fused, processed in two q-halves (register budget) ----
  // S^T tile = mfma(kf, qf): lane holds S[m=quad*4+r][q=ln]; exp in f32;
  // row-sum is in-lane + 2 shfl_xor (rows are lane-local); P packed over
  // m-pairs feeds PV via build_frag; normalization folded into AO store.
#pragma unroll
  for (int tmh = 0; tmh < 2; ++tmh) {
    Frag qf[2];
#pragma unroll
    for (int t2 = 0; t2 < 2; ++t2) {
      int tm = 2 * tmh + t2;
      build_frag(qf[t2].u, qx[tm][0], qy[tm][0], qx[tm][1], qy[tm][1], quad, ln);
    }
    f32x4 o[2][2];
#pragma unroll
    for (int t2 = 0; t2 < 2; ++t2)
#pragma unroll
      for (int tc = 0; tc < 2; ++tc) { f32x4 z = {0.f,0.f,0.f,0.f}; o[t2][tc] = z; }
    float rs[2] = {0.f, 0.f};

#pragma unroll
    for (int tnp = 0; tnp < 2; ++tnp) {
      u32 px[2][2], py[2][2];   // [tn2][t2], packed over m-pairs
#pragma unroll
      for (int tn2 = 0; tn2 < 2; ++tn2) {
        int tn = 2 * tnp + tn2;
        Frag kf;
        build_frag(kf.u, kx[tn][0], ky[tn][0], kx[tn][1], ky[tn][1], quad, ln);
#pragma unroll
        for (int t2 = 0; t2 < 2; ++t2) {
          f32x4 z = {0.f, 0.f, 0.f, 0.f};
          f32x4 s4 = __builtin_amdgcn_mfma_f32_16x16x32_bf16(kf.v, qf[t2].v, z, 0, 0, 0);
          const float* cp = cmb + (((size_t)((win << 2) | head)) << 12)
                          + ((2 * tmh + t2) * 16 + ln) * 64 + tn * 16 + quad * 4;
          f32x4 c4 = *(const f32x4*)cp;
          float e0 = __expf(s4[0] + c4[0]);
          float e1 = __expf(s4[1] + c4[1]);
          float e2 = __expf(s4[2] + c4[2]);
          float e3 = __expf(s4[3] + c4[3]);
          rs[t2] += (e0 + e1) + (e2 + e3);
          px[tn2][t2] = pack2(e0, e1);
          py[tn2][t2] = pack2(e2, e3);
        }
      }
      // PV over this 32-wide m-slice
      Frag pa[2];
#pragma unroll
      for (int t2 = 0; t2 < 2; ++t2)
        build_frag(pa[t2].u, px[0][t2], py[0][t2], px[1][t2], py[1][t2], quad, ln);
#pragma unroll
      for (int tc = 0; tc < 2; ++tc) {
        Frag bv;
        build_frag(bv.u, vbx[2 * tnp][tc], vby[2 * tnp][tc],
                   vbx[2 * tnp + 1][tc], vby[2 * tnp + 1][tc], quad, ln);
#pragma unroll
        for (int t2 = 0; t2 < 2; ++t2)
          o[t2][tc] = __builtin_amdgcn_mfma_f32_16x16x32_bf16(pa[t2].v, bv.v, o[t2][tc], 0, 0, 0);
      }
    }

    // row-sum finish + normalized AO store (head-private region, no barrier)
#pragma unroll
    for (int t2 = 0; t2 < 2; ++t2) {
      float t = rs[t2];
      t += __shfl_xor(t, 16);
      t += __shfl_xor(t, 32);
      float iv = 1.0f / fmaxf(t, 1e-30f);   // padded rows: 1/0 -> clamp, o=0 anyway
#pragma unroll
      for (int r = 0; r < 4; ++r) {
        float ivr = __shfl(iv, quad * 4 + r);   // inv of local row quad*4+r
        int row = (2 * tmh + t2) * 16 + quad * 4 + r;
#pragma unroll
        for (int tc = 0; tc < 2; ++tc)
          lds[AOFF + head * 2304 + row * 36 + tc * 16 + ln] = f2bf(o[t2][tc][r] * ivr);
      }
    }
  }
  __syncthreads();   // #2: AO of all heads visible

  // ---- Phase E: out = AO @ proj_w + proj_b ----
  {
    bf16x8 aof[4][4];
#pragma unroll
    for (int tm = 0; tm < 4; ++tm)
#pragma unroll
      for (int ks = 0; ks < 4; ++ks)
        aof[tm][ks] = ld8(&lds[AOFF + ks * 2304 + (tm * 16 + ln) * 36 + quad * 8]);
#pragma unroll
    for (int tj = 0; tj < 2; ++tj) {
      int colg = head * 32 + tj * 16 + ln;
      bf16x8 bw[4];
#pragma unroll
      for (int ks = 0; ks < 4; ++ks)
        bw[ks] = ld8(wprojT + colg * 128 + ks * 32 + quad * 8);
      float pb = proj_b[colg];
#pragma unroll
      for (int tm = 0; tm < 4; ++tm) {
        f32x4 acc = {0.f, 0.f, 0.f, 0.f};
#pragma unroll
        for (int ks = 0; ks < 4; ++ks)
          acc = __builtin_amdgcn_mfma_f32_16x16x32_bf16(aof[tm][ks], bw[ks], acc, 0, 0, 0);
        int row0 = tm * 16 + quad * 4;
#pragma unroll
        for (int r = 0; r < 4; ++r) {
          int rr = row0 + r;
          if (rr < NTOK)
            out[((size_t)b * NTOK + rr) * CDIM + colg] = acc[r] + pb;
        }
      }
    }
  }
}

extern "C" void kernel_launch(void* const* d_in, const int* in_sizes, int n_in,
                              void* d_out, int out_size, void* d_ws, size_t ws_size,
                              hipStream_t stream) {
  const float* x          = (const float*)d_in[0];
  const float* qkv_w      = (const float*)d_in[1];
  const float* qkv_b      = (const float*)d_in[2];
  const float* proj_w     = (const float*)d_in[3];
  const float* proj_b     = (const float*)d_in[4];
  const float* bias_table = (const float*)d_in[5];
  const float* mask       = (const float*)d_in[6];
  const int*   rel_index  = (const int*)d_in[7];

  u16*   wqkvT  = (u16*)d_ws;
  u16*   wprojT = wqkvT + 384 * 128;
  float* cmb    = (float*)((char*)d_ws + 131072);

  const int Bt = in_sizes[0] / (NTOK * CDIM);   // 4096

  prep_kernel<<<4096, 256, 0, stream>>>(qkv_w, proj_w, bias_table, mask, rel_index,
                                        wqkvT, wprojT, cmb);
  swin_fused<<<Bt, 256, 0, stream>>>(x, qkv_b, proj_b, wqkvT, wprojT, cmb, (float*)d_out);
}

// Round 4
// 333.064 us; speedup vs baseline: 1.2826x; 1.2826x over previous
//
#include <hip/hip_runtime.h>

#define NTOK 49
#define CDIM 128
#define NH 4
#define NWIN 64

typedef unsigned short u16;
typedef unsigned int u32;
typedef __bf16 bf16x8 __attribute__((ext_vector_type(8)));
typedef float f32x4 __attribute__((ext_vector_type(4)));
typedef u16 u16x4 __attribute__((ext_vector_type(4)));

// RNE f32->bf16 via compiler cast (1 VALU op).
__device__ __forceinline__ u16 f2bf(float f) {
  union { __bf16 h; u16 u; } c;
  c.h = (__bf16)f;
  return c.u;
}
__device__ __forceinline__ u32 pack2(float a, float b) {
  return (u32)f2bf(a) | ((u32)f2bf(b) << 16);
}
__device__ __forceinline__ bf16x8 ld8(const u16* p) { return *(const bf16x8*)p; }

// DPP add across the 16-lane row: xor1, xor2 (quad_perm), then ror4 + ror8.
#define DPP_ADD(v, ctrl)                                                            \
  v += __int_as_float(__builtin_amdgcn_update_dpp(0, __float_as_int(v), ctrl, 0xf, 0xf, true))

// ---------------- prep: transpose weights to bf16, build TRANSPOSED combined bias+mask ----
// ws layout (bytes): [0,98304) wqkvT bf16 (384x128)  [98304,131072) wprojT bf16 (128x128)
//                    [131072,131072+4MB) cmbT f32 [win][h][m(key) 64][n(query) 64], -1e30 pads
__global__ void prep_kernel(const float* __restrict__ qkv_w,
                            const float* __restrict__ proj_w,
                            const float* __restrict__ bias_table,
                            const float* __restrict__ mask,
                            const int* __restrict__ rel_index,
                            u16* __restrict__ wqkvT,
                            u16* __restrict__ wprojT,
                            float* __restrict__ cmbT) {
  int i = blockIdx.x * 256 + threadIdx.x;   // 1,048,576 threads
  if (i < 384 * 128) {
    int n = i >> 7, k = i & 127;
    wqkvT[i] = f2bf(qkv_w[k * 384 + n]);
  }
  if (i < 128 * 128) {
    int n = i >> 7, k = i & 127;
    wprojT[i] = f2bf(proj_w[k * 128 + n]);
  }
  int n = i & 63, m = (i >> 6) & 63, hh = (i >> 12) & 3, win = i >> 14;
  float v = -1e30f;
  if (n < NTOK && m < NTOK)
    v = bias_table[rel_index[n * NTOK + m] * NH + hh] + mask[(win * NTOK + n) * NTOK + m];
  cmbT[i] = v;   // cmbT[win][h][m][n], coalesced in n
}

// ---------------- fused window attention ----------------
// R0 structure (4 waves = 4 heads, Q/K/P in LDS, V in regs) with the LDS
// footprint compacted to 40768 B -> 4 blocks/CU (16 waves, 50% occ cap):
//  * XB stores only 49 rows; rows 49..63 handled by predicated frag reads
//    (row 48+ln exists only for ln==0) -> fragments are exact zeros.
//  * P (49x68 <= 3332 u16, writes guarded row<49) overlays Q+K (3528 u16).
//  * AO (49x36, guarded) overlays P head. All overlays are wave-private;
//    in-wave DS ordering makes read-before-overwrite safe.
//
// LDS map (u16 units, 20384 total = 40768 B):
//   R(h) = h*3528:
//     Q : R(h)        + row*36 + d   (rows<49, d=0..31)
//     K : R(h) + 1764 + row*36 + d   (rows<49)
//     P : R(h)        + row*68 + m   (rows<49) -- overlays Q+K after reads
//     AO: R(h)        + row*36 + d   (rows<49) -- overlays P after reads
//   XB [14112, 20384): x bf16 49x128, xor-swizzled 16B chunks
#define RGN(h) ((h) * 3528)
#define XOFF 14112

__device__ __forceinline__ int xsw(int row, int col) {
  return (row << 7) + ((((col >> 3) ^ (row & 15)) << 3) | (col & 7));
}

__global__ __launch_bounds__(256, 4)
void swin_fused(const float* __restrict__ x, const float* __restrict__ qkv_b,
                const float* __restrict__ proj_b, const u16* __restrict__ wqkvT,
                const u16* __restrict__ wprojT, const float* __restrict__ cmbT,
                float* __restrict__ out) {
  __shared__ u16 lds[20384];
  const int tid  = threadIdx.x;
  const int w    = tid >> 6;       // wave = head
  const int lane = tid & 63;
  const int ln   = lane & 15;
  const int quad = lane >> 4;
  const int b    = blockIdx.x;
  const int win  = b & (NWIN - 1);
  const float scale = 0.17677669529663687f;  // 32^-0.5
  const bf16x8 zz = {};

  // ---- Phase A: x rows 0..48 -> LDS bf16, coalesced float4 loads ----
  {
    const float4* x4 = (const float4*)(x + (size_t)b * (NTOK * CDIM));
    for (int i = tid; i < (NTOK * CDIM) / 4; i += 256) {
      float4 f = x4[i];
      int e = i << 2;
      int row = e >> 7, col = e & 127;
      u16x4 v;
      v[0] = f2bf(f.x); v[1] = f2bf(f.y); v[2] = f2bf(f.z); v[3] = f2bf(f.w);
      *(u16x4*)&lds[XOFF + xsw(row, col)] = v;
    }
  }
  __syncthreads();   // #1: XB ready

  // ---- Phase B: wave w computes q/k/v of head w. Q,K -> private LDS; V -> registers ----
  u32 vbx[4][2], vby[4][2];   // packed bf16: V tokens (4q+0,4q+1)/(4q+2,4q+3), [tok-tile][dim-tile]
  {
    bf16x8 af[4][4];
#pragma unroll
    for (int tm = 0; tm < 4; ++tm)
#pragma unroll
      for (int ks = 0; ks < 4; ++ks)
        af[tm][ks] = (tm < 3 || ln == 0)
                   ? ld8(&lds[XOFF + xsw(tm * 16 + ln, ks * 32 + quad * 8)]) : zz;

#pragma unroll
    for (int tl = 0; tl < 6; ++tl) {
      int sect = tl >> 1, tc = tl & 1;
      int colg = sect * 128 + w * 32 + tc * 16 + ln;
      bf16x8 bw[4];
#pragma unroll
      for (int ks = 0; ks < 4; ++ks)
        bw[ks] = ld8(wqkvT + colg * 128 + ks * 32 + quad * 8);
      float cb = qkv_b[colg];
#pragma unroll
      for (int tm = 0; tm < 4; ++tm) {
        f32x4 acc = {0.f, 0.f, 0.f, 0.f};
#pragma unroll
        for (int ks = 0; ks < 4; ++ks)
          acc = __builtin_amdgcn_mfma_f32_16x16x32_bf16(af[tm][ks], bw[ks], acc, 0, 0, 0);
        int row0 = tm * 16 + quad * 4;   // C-layout: col=ln, row=quad*4+r
        if (sect == 0) {
#pragma unroll
          for (int r = 0; r < 4; ++r) {
            int rr = row0 + r;
            if (rr < NTOK)
              lds[RGN(w) + rr * 36 + tc * 16 + ln] = f2bf((acc[r] + cb) * scale);
          }
        } else if (sect == 1) {
#pragma unroll
          for (int r = 0; r < 4; ++r) {
            int rr = row0 + r;
            if (rr < NTOK)
              lds[RGN(w) + 1764 + rr * 36 + tc * 16 + ln] = f2bf(acc[r] + cb);
          }
        } else {
          vbx[tm][tc] = pack2(acc[0] + cb, acc[1] + cb);
          vby[tm][tc] = pack2(acc[2] + cb, acc[3] + cb);
        }
      }
    }
  }
  // no barrier: everything below (until phase E) reads only wave-private regions

  // ---- Phase C: S = Q K^T, + bias+mask (cmbT float4), exp, row-sum via DPP,
  //      P (UNNORMALIZED, rows<49) -> private LDS overlaying Q+K ----
  f32x4 s[4][4];
  {
    bf16x8 aq[4];
#pragma unroll
    for (int tm = 0; tm < 4; ++tm)
      aq[tm] = (tm < 3 || ln == 0)
             ? ld8(&lds[RGN(w) + (tm * 16 + ln) * 36 + quad * 8]) : zz;
#pragma unroll
    for (int tn = 0; tn < 4; ++tn) {
      bf16x8 bk = (tn < 3 || ln == 0)
                ? ld8(&lds[RGN(w) + 1764 + (tn * 16 + ln) * 36 + quad * 8]) : zz;
#pragma unroll
      for (int tm = 0; tm < 4; ++tm) {
        f32x4 z = {0.f, 0.f, 0.f, 0.f};
        s[tm][tn] = __builtin_amdgcn_mfma_f32_16x16x32_bf16(aq[tm], bk, z, 0, 0, 0);
      }
    }
  }
  {
    const float* cb = cmbT + ((size_t)((win << 2) | w) << 12);
#pragma unroll
    for (int tm = 0; tm < 4; ++tm) {
#pragma unroll
      for (int tn = 0; tn < 4; ++tn) {
        f32x4 c4 = *(const f32x4*)&cb[(tn * 16 + ln) * 64 + tm * 16 + quad * 4];
        s[tm][tn] += c4;
      }
    }
  }
  float inv[4][4];
#pragma unroll
  for (int tm = 0; tm < 4; ++tm) {
    int row0 = tm * 16 + quad * 4;
#pragma unroll
    for (int r = 0; r < 4; ++r) {
      float e0 = __expf(s[tm][0][r]);
      float e1 = __expf(s[tm][1][r]);
      float e2 = __expf(s[tm][2][r]);
      float e3 = __expf(s[tm][3][r]);
      float t = (e0 + e1) + (e2 + e3);
      DPP_ADD(t, 0xB1);   // quad_perm [1,0,3,2] : xor 1
      DPP_ADD(t, 0x4E);   // quad_perm [2,3,0,1] : xor 2
      DPP_ADD(t, 0x124);  // row_ror:4
      DPP_ADD(t, 0x128);  // row_ror:8
      inv[tm][r] = 1.0f / t;
      int rr = row0 + r;
      if (rr < NTOK) {
        lds[RGN(w) + rr * 68 + 0 * 16 + ln] = f2bf(e0);
        lds[RGN(w) + rr * 68 + 1 * 16 + ln] = f2bf(e1);
        lds[RGN(w) + rr * 68 + 2 * 16 + ln] = f2bf(e2);
        lds[RGN(w) + rr * 68 + 3 * 16 + ln] = f2bf(e3);
      }
    }
  }

  // ---- Phase D: O = P @ V (unnormalized); V B-frags via register shuffle;
  //      scale by 1/rowsum at the store; AO (rows<49) overlays P head ----
  {
    f32x4 o[4][2];
#pragma unroll
    for (int tm = 0; tm < 4; ++tm)
#pragma unroll
      for (int tc = 0; tc < 2; ++tc) { f32x4 z = {0.f,0.f,0.f,0.f}; o[tm][tc] = z; }
#pragma unroll
    for (int ks = 0; ks < 2; ++ks) {
      bf16x8 pa[4];
#pragma unroll
      for (int tm = 0; tm < 4; ++tm)
        pa[tm] = (tm < 3 || ln == 0)
               ? ld8(&lds[RGN(w) + (tm * 16 + ln) * 68 + ks * 32 + quad * 8]) : zz;
#pragma unroll
      for (int tc = 0; tc < 2; ++tc) {
        union { u32 u[4]; bf16x8 v; } bv;
#pragma unroll
        for (int p = 0; p < 4; ++p) {
          int src = ((2 * (quad & 1) + (p >> 1)) << 4) | ln;
          int a0 = __shfl((int)((p & 1) ? vby[2 * ks][tc]     : vbx[2 * ks][tc]),     src);
          int a1 = __shfl((int)((p & 1) ? vby[2 * ks + 1][tc] : vbx[2 * ks + 1][tc]), src);
          bv.u[p] = (u32)((quad < 2) ? a0 : a1);
        }
#pragma unroll
        for (int tm = 0; tm < 4; ++tm)
          o[tm][tc] = __builtin_amdgcn_mfma_f32_16x16x32_bf16(pa[tm], bv.v, o[tm][tc], 0, 0, 0);
      }
    }
#pragma unroll
    for (int tm = 0; tm < 4; ++tm) {
      int row0 = tm * 16 + quad * 4;
#pragma unroll
      for (int tc = 0; tc < 2; ++tc)
#pragma unroll
        for (int r = 0; r < 4; ++r) {
          int rr = row0 + r;
          if (rr < NTOK)
            lds[RGN(w) + rr * 36 + tc * 16 + ln] = f2bf(o[tm][tc][r] * inv[tm][r]);
        }
    }
  }
  __syncthreads();   // #2: AO of all heads visible

  // ---- Phase E: out = AO @ proj_w + proj_b ----
  {
    bf16x8 aof[4][4];
#pragma unroll
    for (int tm = 0; tm < 4; ++tm)
#pragma unroll
      for (int ks = 0; ks < 4; ++ks)
        aof[tm][ks] = (tm < 3 || ln == 0)
                    ? ld8(&lds[RGN(ks) + (tm * 16 + ln) * 36 + quad * 8]) : zz;
#pragma unroll
    for (int tj = 0; tj < 2; ++tj) {
      int colg = w * 32 + tj * 16 + ln;
      bf16x8 bw[4];
#pragma unroll
      for (int ks = 0; ks < 4; ++ks)
        bw[ks] = ld8(wprojT + colg * 128 + ks * 32 + quad * 8);
      float pb = proj_b[colg];
#pragma unroll
      for (int tm = 0; tm < 4; ++tm) {
        f32x4 acc = {0.f, 0.f, 0.f, 0.f};
#pragma unroll
        for (int ks = 0; ks < 4; ++ks)
          acc = __builtin_amdgcn_mfma_f32_16x16x32_bf16(aof[tm][ks], bw[ks], acc, 0, 0, 0);
        int row0 = tm * 16 + quad * 4;
#pragma unroll
        for (int r = 0; r < 4; ++r) {
          int rr = row0 + r;
          if (rr < NTOK)
            out[((size_t)b * NTOK + rr) * CDIM + colg] = acc[r] + pb;
        }
      }
    }
  }
}

extern "C" void kernel_launch(void* const* d_in, const int* in_sizes, int n_in,
                              void* d_out, int out_size, void* d_ws, size_t ws_size,
                              hipStream_t stream) {
  const float* x          = (const float*)d_in[0];
  const float* qkv_w      = (const float*)d_in[1];
  const float* qkv_b      = (const float*)d_in[2];
  const float* proj_w     = (const float*)d_in[3];
  const float* proj_b     = (const float*)d_in[4];
  const float* bias_table = (const float*)d_in[5];
  const float* mask       = (const float*)d_in[6];
  const int*   rel_index  = (const int*)d_in[7];

  u16*   wqkvT  = (u16*)d_ws;
  u16*   wprojT = wqkvT + 384 * 128;
  float* cmbT   = (float*)((char*)d_ws + 131072);

  const int Bt = in_sizes[0] / (NTOK * CDIM);   // 4096

  prep_kernel<<<4096, 256, 0, stream>>>(qkv_w, proj_w, bias_table, mask, rel_index,
                                        wqkvT, wprojT, cmbT);
  swin_fused<<<Bt, 256, 0, stream>>>(x, qkv_b, proj_b, wqkvT, wprojT, cmbT, (float*)d_out);
}

// Round 5
// 308.376 us; speedup vs baseline: 1.3853x; 1.0801x over previous
//
#include <hip/hip_runtime.h>

#define NTOK 49
#define CDIM 128
#define NH 4
#define NWIN 64

typedef unsigned short u16;
typedef unsigned int u32;
typedef __bf16 bf16x8 __attribute__((ext_vector_type(8)));
typedef float f32x4 __attribute__((ext_vector_type(4)));
typedef u16 u16x4 __attribute__((ext_vector_type(4)));

// RNE f32->bf16 via compiler cast (1 VALU op).
__device__ __forceinline__ u16 f2bf(float f) {
  union { __bf16 h; u16 u; } c;
  c.h = (__bf16)f;
  return c.u;
}
__device__ __forceinline__ u32 pack2(float a, float b) {
  return (u32)f2bf(a) | ((u32)f2bf(b) << 16);
}
__device__ __forceinline__ bf16x8 ld8(const u16* p) { return *(const bf16x8*)p; }

// DPP add across the 16-lane row: xor1, xor2 (quad_perm), then ror4 + ror8.
#define DPP_ADD(v, ctrl)                                                            \
  v += __int_as_float(__builtin_amdgcn_update_dpp(0, __float_as_int(v), ctrl, 0xf, 0xf, true))

// ---------------- prep: transpose weights to bf16, build TRANSPOSED combined bias+mask ----
// ws layout (bytes): [0,98304) wqkvT bf16 (384x128)  [98304,131072) wprojT bf16 (128x128)
//                    [131072,131072+4MB) cmbT f32 [win][h][m(key) 64][n(query) 64], -1e30 pads
__global__ void prep_kernel(const float* __restrict__ qkv_w,
                            const float* __restrict__ proj_w,
                            const float* __restrict__ bias_table,
                            const float* __restrict__ mask,
                            const int* __restrict__ rel_index,
                            u16* __restrict__ wqkvT,
                            u16* __restrict__ wprojT,
                            float* __restrict__ cmbT) {
  int i = blockIdx.x * 256 + threadIdx.x;   // 1,048,576 threads
  if (i < 384 * 128) {
    int n = i >> 7, k = i & 127;
    wqkvT[i] = f2bf(qkv_w[k * 384 + n]);
  }
  if (i < 128 * 128) {
    int n = i >> 7, k = i & 127;
    wprojT[i] = f2bf(proj_w[k * 128 + n]);
  }
  int n = i & 63, m = (i >> 6) & 63, hh = (i >> 12) & 3, win = i >> 14;
  float v = -1e30f;
  if (n < NTOK && m < NTOK)
    v = bias_table[rel_index[n * NTOK + m] * NH + hh] + mask[(win * NTOK + n) * NTOK + m];
  cmbT[i] = v;   // cmbT[win][h][m][n], coalesced in n
}

// ---------------- fused window attention ----------------
// R4 structure (4 waves = 4 heads, Q/K/P in LDS, V in regs; LDS compacted to
// 40768 B -> 4 blocks/CU) with the register budget fixed:
// EMPIRICAL TOOLCHAIN RULE (R0/R2/R3/R4): VGPR cap = 256 / launch_bounds_arg2,
// NOT 512/arg2. (256,4) capped at 64 regs -> spill (WRITE_SIZE 2x). (256,2)
// caps at 128 >= ~90-reg demand -> no spill; occupancy still LDS-bound at
// 4 blocks/CU = 16 waves/CU.
//
// LDS map (u16 units, 20384 total = 40768 B):
//   R(h) = h*3528:
//     Q : R(h)        + row*36 + d   (rows<49, d=0..31)
//     K : R(h) + 1764 + row*36 + d   (rows<49)
//     P : R(h)        + row*68 + m   (rows<49) -- overlays Q+K after reads
//     AO: R(h)        + row*36 + d   (rows<49) -- overlays P after reads
//   XB [14112, 20384): x bf16 49x128, xor-swizzled 16B chunks
#define RGN(h) ((h) * 3528)
#define XOFF 14112

__device__ __forceinline__ int xsw(int row, int col) {
  return (row << 7) + ((((col >> 3) ^ (row & 15)) << 3) | (col & 7));
}

__global__ __launch_bounds__(256, 2)
void swin_fused(const float* __restrict__ x, const float* __restrict__ qkv_b,
                const float* __restrict__ proj_b, const u16* __restrict__ wqkvT,
                const u16* __restrict__ wprojT, const float* __restrict__ cmbT,
                float* __restrict__ out) {
  __shared__ u16 lds[20384];
  const int tid  = threadIdx.x;
  const int w    = tid >> 6;       // wave = head
  const int lane = tid & 63;
  const int ln   = lane & 15;
  const int quad = lane >> 4;
  const int b    = blockIdx.x;
  const int win  = b & (NWIN - 1);
  const float scale = 0.17677669529663687f;  // 32^-0.5
  const bf16x8 zz = {};

  // ---- Phase A: x rows 0..48 -> LDS bf16, coalesced float4 loads ----
  {
    const float4* x4 = (const float4*)(x + (size_t)b * (NTOK * CDIM));
    for (int i = tid; i < (NTOK * CDIM) / 4; i += 256) {
      float4 f = x4[i];
      int e = i << 2;
      int row = e >> 7, col = e & 127;
      u16x4 v;
      v[0] = f2bf(f.x); v[1] = f2bf(f.y); v[2] = f2bf(f.z); v[3] = f2bf(f.w);
      *(u16x4*)&lds[XOFF + xsw(row, col)] = v;
    }
  }
  __syncthreads();   // #1: XB ready

  // ---- Phase B: wave w computes q/k/v of head w. Q,K -> private LDS; V -> registers ----
  u32 vbx[4][2], vby[4][2];   // packed bf16: V tokens (4q+0,4q+1)/(4q+2,4q+3), [tok-tile][dim-tile]
  {
    bf16x8 af[4][4];
#pragma unroll
    for (int tm = 0; tm < 4; ++tm)
#pragma unroll
      for (int ks = 0; ks < 4; ++ks)
        af[tm][ks] = (tm < 3 || ln == 0)
                   ? ld8(&lds[XOFF + xsw(tm * 16 + ln, ks * 32 + quad * 8)]) : zz;

#pragma unroll
    for (int tl = 0; tl < 6; ++tl) {
      int sect = tl >> 1, tc = tl & 1;
      int colg = sect * 128 + w * 32 + tc * 16 + ln;
      bf16x8 bw[4];
#pragma unroll
      for (int ks = 0; ks < 4; ++ks)
        bw[ks] = ld8(wqkvT + colg * 128 + ks * 32 + quad * 8);
      float cb = qkv_b[colg];
#pragma unroll
      for (int tm = 0; tm < 4; ++tm) {
        f32x4 acc = {0.f, 0.f, 0.f, 0.f};
#pragma unroll
        for (int ks = 0; ks < 4; ++ks)
          acc = __builtin_amdgcn_mfma_f32_16x16x32_bf16(af[tm][ks], bw[ks], acc, 0, 0, 0);
        int row0 = tm * 16 + quad * 4;   // C-layout: col=ln, row=quad*4+r
        if (sect == 0) {
#pragma unroll
          for (int r = 0; r < 4; ++r) {
            int rr = row0 + r;
            if (rr < NTOK)
              lds[RGN(w) + rr * 36 + tc * 16 + ln] = f2bf((acc[r] + cb) * scale);
          }
        } else if (sect == 1) {
#pragma unroll
          for (int r = 0; r < 4; ++r) {
            int rr = row0 + r;
            if (rr < NTOK)
              lds[RGN(w) + 1764 + rr * 36 + tc * 16 + ln] = f2bf(acc[r] + cb);
          }
        } else {
          vbx[tm][tc] = pack2(acc[0] + cb, acc[1] + cb);
          vby[tm][tc] = pack2(acc[2] + cb, acc[3] + cb);
        }
      }
    }
  }
  // no barrier: everything below (until phase E) reads only wave-private regions

  // ---- Phase C: S = Q K^T, + bias+mask (cmbT float4), exp, row-sum via DPP,
  //      P (UNNORMALIZED, rows<49) -> private LDS overlaying Q+K ----
  f32x4 s[4][4];
  {
    bf16x8 aq[4];
#pragma unroll
    for (int tm = 0; tm < 4; ++tm)
      aq[tm] = (tm < 3 || ln == 0)
             ? ld8(&lds[RGN(w) + (tm * 16 + ln) * 36 + quad * 8]) : zz;
#pragma unroll
    for (int tn = 0; tn < 4; ++tn) {
      bf16x8 bk = (tn < 3 || ln == 0)
                ? ld8(&lds[RGN(w) + 1764 + (tn * 16 + ln) * 36 + quad * 8]) : zz;
#pragma unroll
      for (int tm = 0; tm < 4; ++tm) {
        f32x4 z = {0.f, 0.f, 0.f, 0.f};
        s[tm][tn] = __builtin_amdgcn_mfma_f32_16x16x32_bf16(aq[tm], bk, z, 0, 0, 0);
      }
    }
  }
  {
    const float* cb = cmbT + ((size_t)((win << 2) | w) << 12);
#pragma unroll
    for (int tm = 0; tm < 4; ++tm) {
#pragma unroll
      for (int tn = 0; tn < 4; ++tn) {
        f32x4 c4 = *(const f32x4*)&cb[(tn * 16 + ln) * 64 + tm * 16 + quad * 4];
        s[tm][tn] += c4;
      }
    }
  }
  float inv[4][4];
#pragma unroll
  for (int tm = 0; tm < 4; ++tm) {
    int row0 = tm * 16 + quad * 4;
#pragma unroll
    for (int r = 0; r < 4; ++r) {
      float e0 = __expf(s[tm][0][r]);
      float e1 = __expf(s[tm][1][r]);
      float e2 = __expf(s[tm][2][r]);
      float e3 = __expf(s[tm][3][r]);
      float t = (e0 + e1) + (e2 + e3);
      DPP_ADD(t, 0xB1);   // quad_perm [1,0,3,2] : xor 1
      DPP_ADD(t, 0x4E);   // quad_perm [2,3,0,1] : xor 2
      DPP_ADD(t, 0x124);  // row_ror:4
      DPP_ADD(t, 0x128);  // row_ror:8
      inv[tm][r] = 1.0f / t;
      int rr = row0 + r;
      if (rr < NTOK) {
        lds[RGN(w) + rr * 68 + 0 * 16 + ln] = f2bf(e0);
        lds[RGN(w) + rr * 68 + 1 * 16 + ln] = f2bf(e1);
        lds[RGN(w) + rr * 68 + 2 * 16 + ln] = f2bf(e2);
        lds[RGN(w) + rr * 68 + 3 * 16 + ln] = f2bf(e3);
      }
    }
  }

  // ---- Phase D: O = P @ V (unnormalized); V B-frags via register shuffle;
  //      scale by 1/rowsum at the store; AO (rows<49) overlays P head ----
  {
    f32x4 o[4][2];
#pragma unroll
    for (int tm = 0; tm < 4; ++tm)
#pragma unroll
      for (int tc = 0; tc < 2; ++tc) { f32x4 z = {0.f,0.f,0.f,0.f}; o[tm][tc] = z; }
#pragma unroll
    for (int ks = 0; ks < 2; ++ks) {
      bf16x8 pa[4];
#pragma unroll
      for (int tm = 0; tm < 4; ++tm)
        pa[tm] = (tm < 3 || ln == 0)
               ? ld8(&lds[RGN(w) + (tm * 16 + ln) * 68 + ks * 32 + quad * 8]) : zz;
#pragma unroll
      for (int tc = 0; tc < 2; ++tc) {
        union { u32 u[4]; bf16x8 v; } bv;
#pragma unroll
        for (int p = 0; p < 4; ++p) {
          int src = ((2 * (quad & 1) + (p >> 1)) << 4) | ln;
          int a0 = __shfl((int)((p & 1) ? vby[2 * ks][tc]     : vbx[2 * ks][tc]),     src);
          int a1 = __shfl((int)((p & 1) ? vby[2 * ks + 1][tc] : vbx[2 * ks + 1][tc]), src);
          bv.u[p] = (u32)((quad < 2) ? a0 : a1);
        }
#pragma unroll
        for (int tm = 0; tm < 4; ++tm)
          o[tm][tc] = __builtin_amdgcn_mfma_f32_16x16x32_bf16(pa[tm], bv.v, o[tm][tc], 0, 0, 0);
      }
    }
#pragma unroll
    for (int tm = 0; tm < 4; ++tm) {
      int row0 = tm * 16 + quad * 4;
#pragma unroll
      for (int tc = 0; tc < 2; ++tc)
#pragma unroll
        for (int r = 0; r < 4; ++r) {
          int rr = row0 + r;
          if (rr < NTOK)
            lds[RGN(w) + rr * 36 + tc * 16 + ln] = f2bf(o[tm][tc][r] * inv[tm][r]);
        }
    }
  }
  __syncthreads();   // #2: AO of all heads visible

  // ---- Phase E: out = AO @ proj_w + proj_b ----
  {
    bf16x8 aof[4][4];
#pragma unroll
    for (int tm = 0; tm < 4; ++tm)
#pragma unroll
      for (int ks = 0; ks < 4; ++ks)
        aof[tm][ks] = (tm < 3 || ln == 0)
                    ? ld8(&lds[RGN(ks) + (tm * 16 + ln) * 36 + quad * 8]) : zz;
#pragma unroll
    for (int tj = 0; tj < 2; ++tj) {
      int colg = w * 32 + tj * 16 + ln;
      bf16x8 bw[4];
#pragma unroll
      for (int ks = 0; ks < 4; ++ks)
        bw[ks] = ld8(wprojT + colg * 128 + ks * 32 + quad * 8);
      float pb = proj_b[colg];
#pragma unroll
      for (int tm = 0; tm < 4; ++tm) {
        f32x4 acc = {0.f, 0.f, 0.f, 0.f};
#pragma unroll
        for (int ks = 0; ks < 4; ++ks)
          acc = __builtin_amdgcn_mfma_f32_16x16x32_bf16(aof[tm][ks], bw[ks], acc, 0, 0, 0);
        int row0 = tm * 16 + quad * 4;
#pragma unroll
        for (int r = 0; r < 4; ++r) {
          int rr = row0 + r;
          if (rr < NTOK)
            out[((size_t)b * NTOK + rr) * CDIM + colg] = acc[r] + pb;
        }
      }
    }
  }
}

extern "C" void kernel_launch(void* const* d_in, const int* in_sizes, int n_in,
                              void* d_out, int out_size, void* d_ws, size_t ws_size,
                              hipStream_t stream) {
  const float* x          = (const float*)d_in[0];
  const float* qkv_w      = (const float*)d_in[1];
  const float* qkv_b      = (const float*)d_in[2];
  const float* proj_w     = (const float*)d_in[3];
  const float* proj_b     = (const float*)d_in[4];
  const float* bias_table = (const float*)d_in[5];
  const float* mask       = (const float*)d_in[6];
  const int*   rel_index  = (const int*)d_in[7];

  u16*   wqkvT  = (u16*)d_ws;
  u16*   wprojT = wqkvT + 384 * 128;
  float* cmbT   = (float*)((char*)d_ws + 131072);

  const int Bt = in_sizes[0] / (NTOK * CDIM);   // 4096

  prep_kernel<<<4096, 256, 0, stream>>>(qkv_w, proj_w, bias_table, mask, rel_index,
                                        wqkvT, wprojT, cmbT);
  swin_fused<<<Bt, 256, 0, stream>>>(x, qkv_b, proj_b, wqkvT, wprojT, cmbT, (float*)d_out);
}

// Round 6
// 289.328 us; speedup vs baseline: 1.4765x; 1.0658x over previous
//
#include <hip/hip_runtime.h>

#define NTOK 49
#define CDIM 128
#define NH 4
#define NWIN 64

typedef unsigned short u16;
typedef unsigned int u32;
typedef __bf16 bf16x8 __attribute__((ext_vector_type(8)));
typedef float f32x4 __attribute__((ext_vector_type(4)));
typedef u16 u16x4 __attribute__((ext_vector_type(4)));

union Frag { u32 u[4]; bf16x8 v; };

// RNE f32->bf16 via compiler cast (1 VALU op).
__device__ __forceinline__ u16 f2bf(float f) {
  union { __bf16 h; u16 u; } c;
  c.h = (__bf16)f;
  return c.u;
}
__device__ __forceinline__ u32 pack2(float a, float b) {
  return (u32)f2bf(a) | ((u32)f2bf(b) << 16);
}
__device__ __forceinline__ bf16x8 ld8(const u16* p) { return *(const bf16x8*)p; }

// Convert C-layout register pairs (pairs over quad*4+{r,r+1}, two 16-tiles)
// into an MFMA A/B fragment k-slice. Proven by R0's V path; reused for P.
__device__ __forceinline__ void build_frag(u32 u[4], u32 x0, u32 y0, u32 x1, u32 y1,
                                           int quad, int ln) {
#pragma unroll
  for (int p = 0; p < 4; ++p) {
    int src = ((2 * (quad & 1) + (p >> 1)) << 4) | ln;
    int a0 = __shfl((int)((p & 1) ? y0 : x0), src);
    int a1 = __shfl((int)((p & 1) ? y1 : x1), src);
    u[p] = (u32)((quad < 2) ? a0 : a1);
  }
}

// ---------------- prep: transpose weights to bf16, build combined bias+mask ----
// ws layout (bytes): [0,98304) wqkvT bf16 (384x128)  [98304,131072) wprojT bf16 (128x128)
//                    [131072,131072+4MB) cmb f32 [win][h][q 64][m 64], -1e30 pads
// NOTE: cmb is NON-transposed now ([q][m]) because S is computed as S^T
// (col=q per lane, m over quad*4+r regs) -> f32x4 loads run along m.
__global__ void prep_kernel(const float* __restrict__ qkv_w,
                            const float* __restrict__ proj_w,
                            const float* __restrict__ bias_table,
                            const float* __restrict__ mask,
                            const int* __restrict__ rel_index,
                            u16* __restrict__ wqkvT,
                            u16* __restrict__ wprojT,
                            float* __restrict__ cmb) {
  int i = blockIdx.x * 256 + threadIdx.x;   // 1,048,576 threads
  if (i < 384 * 128) {
    int n = i >> 7, k = i & 127;
    wqkvT[i] = f2bf(qkv_w[k * 384 + n]);
  }
  if (i < 128 * 128) {
    int n = i >> 7, k = i & 127;
    wprojT[i] = f2bf(proj_w[k * 128 + n]);
  }
  int m = i & 63, q = (i >> 6) & 63, hh = (i >> 12) & 3, win = i >> 14;
  float v = -1e30f;
  if (q < NTOK && m < NTOK)
    v = bias_table[rel_index[q * NTOK + m] * NH + hh] + mask[(win * NTOK + q) * NTOK + m];
  cmb[i] = v;   // cmb[win][h][q][m], coalesced in m
}

// ---------------- fused window attention ----------------
// 4 waves = 4 heads. Q,K staged in LDS (transpose via store); V in registers.
// S computed TRANSPOSED: s = mfma(K_frag, Q_frag) -> lane ln owns softmax row
// q = tile*16+ln, m spread over quad*4+r regs. Row-sum = in-lane adds + 2
// shfl_xor; 1/sum is lane-local, folded into P at pack2. P converted to the
// PV A-fragment by the same build_frag shuffle as V -> P NEVER touches LDS
// (removes 64 b16 stores + 8 b128 loads + 64-DPP chain per wave).
//
// LDS map (u16 units, 26624 total = 53248 B -> 3 blocks/CU):
//   XB [0,8192): x bf16 64x128, xor-swizzled 16B chunks (read-only after A)
//   R(h) = 8192 + h*4608:
//     Q : R(h)        + row*36 + d   (64x36, d=0..31)
//     K : R(h) + 2304 + row*36 + d
//     AO: R(h)        + row*36 + d   -- overlays Q after phase-C reads
#define RGN(h) (8192 + (h) * 4608)

__device__ __forceinline__ int xsw(int row, int col) {
  return (row << 7) + ((((col >> 3) ^ (row & 15)) << 3) | (col & 7));
}

__global__ __launch_bounds__(256, 2)
void swin_fused(const float* __restrict__ x, const float* __restrict__ qkv_b,
                const float* __restrict__ proj_b, const u16* __restrict__ wqkvT,
                const u16* __restrict__ wprojT, const float* __restrict__ cmb,
                float* __restrict__ out) {
  __shared__ u16 lds[26624];
  const int tid  = threadIdx.x;
  const int w    = tid >> 6;       // wave = head
  const int lane = tid & 63;
  const int ln   = lane & 15;
  const int quad = lane >> 4;
  const int b    = blockIdx.x;
  const int win  = b & (NWIN - 1);
  const float scale = 0.17677669529663687f;  // 32^-0.5

  // ---- Phase A: x -> LDS bf16 (rows 49..63 zeroed), coalesced float4 loads ----
  {
    const float4* x4 = (const float4*)(x + (size_t)b * (NTOK * CDIM));
    for (int i = tid; i < (NTOK * CDIM) / 4; i += 256) {
      float4 f = x4[i];
      int e = i << 2;
      int row = e >> 7, col = e & 127;
      u16x4 v;
      v[0] = f2bf(f.x); v[1] = f2bf(f.y); v[2] = f2bf(f.z); v[3] = f2bf(f.w);
      *(u16x4*)&lds[xsw(row, col)] = v;
    }
    for (int i = tid; i < (15 * CDIM) / 4; i += 256) {
      int e = i << 2;
      int row = NTOK + (e >> 7), col = e & 127;
      u16x4 v = {0, 0, 0, 0};
      *(u16x4*)&lds[xsw(row, col)] = v;
    }
  }
  __syncthreads();   // #1: XB ready

  // ---- Phase B: wave w computes q/k/v of head w. Q,K -> private LDS; V -> registers ----
  u32 vbx[4][2], vby[4][2];   // packed bf16: V tokens (4q+0,4q+1)/(4q+2,4q+3), [tok-tile][dim-tile]
  {
    bf16x8 af[4][4];
#pragma unroll
    for (int tm = 0; tm < 4; ++tm)
#pragma unroll
      for (int ks = 0; ks < 4; ++ks)
        af[tm][ks] = ld8(&lds[xsw(tm * 16 + ln, ks * 32 + quad * 8)]);

#pragma unroll
    for (int tl = 0; tl < 6; ++tl) {
      int sect = tl >> 1, tc = tl & 1;
      int colg = sect * 128 + w * 32 + tc * 16 + ln;
      bf16x8 bw[4];
#pragma unroll
      for (int ks = 0; ks < 4; ++ks)
        bw[ks] = ld8(wqkvT + colg * 128 + ks * 32 + quad * 8);
      float cb = qkv_b[colg];
#pragma unroll
      for (int tm = 0; tm < 4; ++tm) {
        f32x4 acc = {0.f, 0.f, 0.f, 0.f};
#pragma unroll
        for (int ks = 0; ks < 4; ++ks)
          acc = __builtin_amdgcn_mfma_f32_16x16x32_bf16(af[tm][ks], bw[ks], acc, 0, 0, 0);
        int row0 = tm * 16 + quad * 4;   // C-layout: col=ln, row=quad*4+r
        if (sect == 0) {
#pragma unroll
          for (int r = 0; r < 4; ++r)
            lds[RGN(w) + (row0 + r) * 36 + tc * 16 + ln] = f2bf((acc[r] + cb) * scale);
        } else if (sect == 1) {
#pragma unroll
          for (int r = 0; r < 4; ++r)
            lds[RGN(w) + 2304 + (row0 + r) * 36 + tc * 16 + ln] = f2bf(acc[r] + cb);
        } else {
          vbx[tm][tc] = pack2(acc[0] + cb, acc[1] + cb);
          vby[tm][tc] = pack2(acc[2] + cb, acc[3] + cb);
        }
      }
    }
  }
  // no barrier: phases C/D read only wave-private regions + registers

  // ---- Phase C+D: S^T = mfma(K,Q); bias+exp; lane-local rowsum; P in regs -> PV ----
  {
    bf16x8 aq[4], bk[4];
#pragma unroll
    for (int t = 0; t < 4; ++t) {
      aq[t] = ld8(&lds[RGN(w) + (t * 16 + ln) * 36 + quad * 8]);
      bk[t] = ld8(&lds[RGN(w) + 2304 + (t * 16 + ln) * 36 + quad * 8]);
    }
    f32x4 s[4][4];   // s[tm][tn][r] = S[m=tn*16+quad*4+r][q=tm*16+ln]
#pragma unroll
    for (int tn = 0; tn < 4; ++tn)
#pragma unroll
      for (int tm = 0; tm < 4; ++tm) {
        f32x4 z = {0.f, 0.f, 0.f, 0.f};
        s[tm][tn] = __builtin_amdgcn_mfma_f32_16x16x32_bf16(bk[tn], aq[tm], z, 0, 0, 0);
      }

    // V B-fragments (register shuffle, as in R0)
    Frag bv[2][2];
#pragma unroll
    for (int ks = 0; ks < 2; ++ks)
#pragma unroll
      for (int tc = 0; tc < 2; ++tc)
        build_frag(bv[ks][tc].u, vbx[2 * ks][tc], vby[2 * ks][tc],
                   vbx[2 * ks + 1][tc], vby[2 * ks + 1][tc], quad, ln);

    const float* cbp = cmb + ((size_t)((win << 2) | w) << 12);
#pragma unroll
    for (int tm = 0; tm < 4; ++tm) {
      // bias + exp over this q-column's 64 m values (16 in-lane x 4 quads)
      float e[4][4];
      float tsum = 0.f;
#pragma unroll
      for (int tn = 0; tn < 4; ++tn) {
        f32x4 c4 = *(const f32x4*)&cbp[(tm * 16 + ln) * 64 + tn * 16 + quad * 4];
#pragma unroll
        for (int r = 0; r < 4; ++r)
          e[tn][r] = __expf(s[tm][tn][r] + c4[r]);
        tsum += (e[tn][0] + e[tn][1]) + (e[tn][2] + e[tn][3]);
      }
      tsum += __shfl_xor(tsum, 16);
      tsum += __shfl_xor(tsum, 32);
      float iv = 1.0f / fmaxf(tsum, 1e-30f);   // pad q-rows: sum=0 -> o=0 anyway

      // normalized P, packed over m-pairs (same structure as V packs)
      u32 px[4], py[4];
#pragma unroll
      for (int tn = 0; tn < 4; ++tn) {
        px[tn] = pack2(e[tn][0] * iv, e[tn][1] * iv);
        py[tn] = pack2(e[tn][2] * iv, e[tn][3] * iv);
      }

      // PV for this q-tile
      f32x4 o[2];
#pragma unroll
      for (int tc = 0; tc < 2; ++tc) { f32x4 z = {0.f,0.f,0.f,0.f}; o[tc] = z; }
#pragma unroll
      for (int ks = 0; ks < 2; ++ks) {
        Frag pa;
        build_frag(pa.u, px[2 * ks], py[2 * ks], px[2 * ks + 1], py[2 * ks + 1], quad, ln);
#pragma unroll
        for (int tc = 0; tc < 2; ++tc)
          o[tc] = __builtin_amdgcn_mfma_f32_16x16x32_bf16(pa.v, bv[ks][tc].v, o[tc], 0, 0, 0);
      }

      // AO store (normalized; overlays Q region -- aq reads are done)
      int row0 = tm * 16 + quad * 4;
#pragma unroll
      for (int tc = 0; tc < 2; ++tc)
#pragma unroll
        for (int r = 0; r < 4; ++r)
          lds[RGN(w) + (row0 + r) * 36 + tc * 16 + ln] = f2bf(o[tc][r]);
    }
  }
  __syncthreads();   // #2: AO of all heads visible

  // ---- Phase E: out = AO @ proj_w + proj_b ----
  {
    bf16x8 aof[4][4];
#pragma unroll
    for (int tm = 0; tm < 4; ++tm)
#pragma unroll
      for (int ks = 0; ks < 4; ++ks)
        aof[tm][ks] = ld8(&lds[RGN(ks) + (tm * 16 + ln) * 36 + quad * 8]);
#pragma unroll
    for (int tj = 0; tj < 2; ++tj) {
      int colg = w * 32 + tj * 16 + ln;
      bf16x8 bw[4];
#pragma unroll
      for (int ks = 0; ks < 4; ++ks)
        bw[ks] = ld8(wprojT + colg * 128 + ks * 32 + quad * 8);
      float pb = proj_b[colg];
#pragma unroll
      for (int tm = 0; tm < 4; ++tm) {
        f32x4 acc = {0.f, 0.f, 0.f, 0.f};
#pragma unroll
        for (int ks = 0; ks < 4; ++ks)
          acc = __builtin_amdgcn_mfma_f32_16x16x32_bf16(aof[tm][ks], bw[ks], acc, 0, 0, 0);
        int row0 = tm * 16 + quad * 4;
#pragma unroll
        for (int r = 0; r < 4; ++r) {
          int rr = row0 + r;
          if (rr < NTOK)
            out[((size_t)b * NTOK + rr) * CDIM + colg] = acc[r] + pb;
        }
      }
    }
  }
}

extern "C" void kernel_launch(void* const* d_in, const int* in_sizes, int n_in,
                              void* d_out, int out_size, void* d_ws, size_t ws_size,
                              hipStream_t stream) {
  const float* x          = (const float*)d_in[0];
  const float* qkv_w      = (const float*)d_in[1];
  const float* qkv_b      = (const float*)d_in[2];
  const float* proj_w     = (const float*)d_in[3];
  const float* proj_b     = (const float*)d_in[4];
  const float* bias_table = (const float*)d_in[5];
  const float* mask       = (const float*)d_in[6];
  const int*   rel_index  = (const int*)d_in[7];

  u16*   wqkvT  = (u16*)d_ws;
  u16*   wprojT = wqkvT + 384 * 128;
  float* cmb    = (float*)((char*)d_ws + 131072);

  const int Bt = in_sizes[0] / (NTOK * CDIM);   // 4096

  prep_kernel<<<4096, 256, 0, stream>>>(qkv_w, proj_w, bias_table, mask, rel_index,
                                        wqkvT, wprojT, cmb);
  swin_fused<<<Bt, 256, 0, stream>>>(x, qkv_b, proj_b, wqkvT, wprojT, cmb, (float*)d_out);
}